// Round 3
// baseline (165.554 us; speedup 1.0000x reference)
//
#include <hip/hip_runtime.h>
#include <math.h>

#define S_ 6
#define N_ 10000
#define C_ 128
#define D_ 4
#define H_ 4
#define P_ 8
#define HF_ 28
#define WF_ 50
#define M_ (HF_ * WF_)   // 1400
#define DH_ 32
#define SM_ (S_ * M_)    // 8400
// one fp8 value-copy: S*H*M pixels x 32 B = 1,075,200 B
#define ABYTES (S_ * H_ * M_ * 32)
#define VB_SH (M_ * 32)          // 44,800 B per (s,h) plane
#define NSH (S_ * H_)            // 24
#define CQ 256                   // queries per attn3 block
#define NCH ((N_ + CQ - 1) / CQ) // 40

#define NB_V ((SM_ + 31) / 32)   // 263 vproj blocks
#define NB_O ((N_ + 31) / 32)    // 313 OFFL blocks

typedef float floatx2 __attribute__((ext_vector_type(2)));
typedef _Float16 half2h __attribute__((ext_vector_type(2)));

// ---------------------------------------------------------------------------
// Shared GEMM body, K=128, MRx4 micro-tile, k-blocked by 4 with ds_read_b128.
//   MODE 0 (vproj): out = A@B0 + bias0 -> fp8 e4m3 (single copy).
//   MODE 1 (OFFL):  out = (A+A2)@[B0|B1] + [bias0|bias1] -> fp32 (Mrows,96).
// ---------------------------------------------------------------------------
template <int NC, int MT, int MR, int MODE>
__device__ __forceinline__ void gemm_body(
    const float* __restrict__ A, const float* __restrict__ A2,
    const float* __restrict__ B0, const float* __restrict__ B1,
    const float* __restrict__ bias0, const float* __restrict__ bias1,
    float* __restrict__ outf, char* __restrict__ out8,
    int Mrows, int m0, int tid, int nthreads, float (*Alds)[132]) {
  constexpr int NTHR = (NC / 4) * (MT / MR);

  for (int i = tid; i < MT * 32; i += nthreads) {
    int r = i >> 5, k = (i & 31) * 4;
    int row = m0 + r;
    float4 v = make_float4(0.f, 0.f, 0.f, 0.f);
    if (row < Mrows) {
      v = *(const float4*)(A + (size_t)row * C_ + k);
      if (MODE == 1) {
        float4 v2 = *(const float4*)(A2 + (size_t)row * C_ + k);
        v.x += v2.x; v.y += v2.y; v.z += v2.z; v.w += v2.w;
      }
    }
    *(float4*)(&Alds[r][k]) = v;
  }
  __syncthreads();
  if (tid >= NTHR) return;

  int ci = tid % (NC / 4);
  int mi = tid / (NC / 4);
  int c0 = ci * 4, r0 = mi * MR;

  const float* bs;
  if (MODE == 1) bs = (c0 < 64) ? bias0 + c0 : bias1 + (c0 - 64);
  else bs = bias0 + c0;

  float acc[MR][4];
#pragma unroll
  for (int j = 0; j < MR; ++j)
#pragma unroll
    for (int cc = 0; cc < 4; ++cc) acc[j][cc] = bs[cc];

#pragma unroll 2
  for (int k4 = 0; k4 < C_; k4 += 4) {
    float bf[16];
#pragma unroll
    for (int kk = 0; kk < 4; ++kk) {
      int k = k4 + kk;
      float4 b4;
      if (MODE == 1)
        b4 = (c0 < 64) ? *(const float4*)(B0 + (size_t)k * 64 + c0)
                       : *(const float4*)(B1 + (size_t)k * 32 + (c0 - 64));
      else
        b4 = *(const float4*)(B0 + (size_t)k * NC + c0);
      bf[kk * 4 + 0] = b4.x; bf[kk * 4 + 1] = b4.y;
      bf[kk * 4 + 2] = b4.z; bf[kk * 4 + 3] = b4.w;
    }
    float af[MR * 4];
#pragma unroll
    for (int j = 0; j < MR; ++j) {
      float4 a4 = *(const float4*)(&Alds[r0 + j][k4]);
      af[j * 4 + 0] = a4.x; af[j * 4 + 1] = a4.y;
      af[j * 4 + 2] = a4.z; af[j * 4 + 3] = a4.w;
    }
#pragma unroll
    for (int j = 0; j < MR; ++j)
#pragma unroll
      for (int kk = 0; kk < 4; ++kk)
#pragma unroll
        for (int cc = 0; cc < 4; ++cc)
          acc[j][cc] = fmaf(af[j * 4 + kk], bf[kk * 4 + cc], acc[j][cc]);
  }

#pragma unroll
  for (int j = 0; j < MR; ++j) {
    int row = m0 + r0 + j;
    if (row >= Mrows) continue;
    if (MODE == 0) {
      int mm = row % M_;
      int h = c0 >> 5, d0 = c0 & 31;
      int s = row / M_;
      int w = __builtin_amdgcn_cvt_pk_fp8_f32(acc[j][0], acc[j][1], 0, false);
      w = __builtin_amdgcn_cvt_pk_fp8_f32(acc[j][2], acc[j][3], w, true);
      size_t hm = (size_t)s * H_ + h;
      *(int*)(out8 + (hm * M_ + mm) * 32 + d0) = w;
    } else if (MODE == 1) {
      *(float4*)(outf + (size_t)row * 96 + c0) =
          make_float4(acc[j][0], acc[j][1], acc[j][2], acc[j][3]);
    }
  }
}

// ---------------------------------------------------------------------------
__global__ __launch_bounds__(256) void prep_kernel(
    const float* __restrict__ value, const float* __restrict__ w_val,
    const float* __restrict__ b_val, char* __restrict__ vh8,
    const float* __restrict__ query, const float* __restrict__ query_pos,
    const float* __restrict__ w_off, const float* __restrict__ b_off,
    const float* __restrict__ w_attn, const float* __restrict__ b_attn,
    float* __restrict__ OFFL) {
  __shared__ float Alds[32][132];
  int bid = blockIdx.x;
  if (bid < NB_V) {
    gemm_body<128, 32, 4, 0>(value, nullptr, w_val, nullptr, b_val, nullptr,
                             nullptr, vh8, SM_, bid * 32, threadIdx.x, 256,
                             Alds);
  } else {
    gemm_body<96, 32, 4, 1>(query, query_pos, w_off, w_attn, b_off, b_attn,
                            OFFL, nullptr, N_, (bid - NB_V) * 32, threadIdx.x,
                            256, Alds);
  }
}

// ---------------------------------------------------------------------------
// attn3: block = (s,h) x 256-query chunk. Stage V[s,h] (44.8 KB) in LDS once;
// the 114x-reused gather becomes ds_read_b128 (~5 cy) instead of ~250 cy L2.
// Lanes: 8 queries x 8 roles (rowsel,xsel,chalf); p-fold free via per-lane
// accumulation; 2 shuffle folds (xsel bit1, rowsel bit2). Partial per-(s,h)
// 32-ch outputs (weights already carry aw*smask) go to ws for the reducer.
// ---------------------------------------------------------------------------
__global__ __launch_bounds__(256, 2) void attn3_kernel(
    const float* __restrict__ OFFL,     // (N,96): [0:64)=off, [64:96)=logits
    const float* __restrict__ refpts,   // (S,1,N,D,2)
    const int*   __restrict__ bev_mask, // (S,1,N,D)
    const char*  __restrict__ wsbase,   // value fp8 at +64, (sh,M,32B)
    float* __restrict__ part) {         // (24, N, 32) fp32 partials
  __shared__ int4 Vl4[VB_SH / 16];      // 44,800 B
  __shared__ int4 Pp[CQ * 9];           // stride 9 -> conflict-free; 36,864 B

  int bid = blockIdx.x;
  int sh = bid % NSH;
  int q0 = (bid / NSH) * CQ;
  int s = sh >> 2, h = sh & 3;
  int tid = threadIdx.x;

  // ---- stage V[s,h] ------------------------------------------------------
  const int4* vsrc = (const int4*)(wsbase + 64 + (size_t)sh * VB_SH);
#pragma unroll 4
  for (int i = tid; i < VB_SH / 16; i += 256) Vl4[i] = vsrc[i];

  // ---- per-(q,p) params: thread t -> query q0+t --------------------------
  {
    int q = q0 + tid;
    float aw[8], rx[4], ry[4];
    int sm = 0;
    if (q < N_) {
      const float* lg = OFFL + (size_t)q * 96 + 64 + h * 8;
      float mx = -1e30f;
#pragma unroll
      for (int p = 0; p < 8; ++p) mx = fmaxf(mx, lg[p]);
      float sum = 0.f;
#pragma unroll
      for (int p = 0; p < 8; ++p) { aw[p] = expf(lg[p] - mx); sum += aw[p]; }
      float is = 1.f / sum;
#pragma unroll
      for (int p = 0; p < 8; ++p) aw[p] *= is;
      const int* bm = bev_mask + ((size_t)s * N_ + q) * D_;
      sm = (bm[0] | bm[1] | bm[2] | bm[3]) ? 1 : 0;
      const float* rf = refpts + ((size_t)s * N_ + q) * 8;
#pragma unroll
      for (int dd = 0; dd < 4; ++dd) {
        rx[dd] = rf[dd * 2 + 0];
        ry[dd] = rf[dd * 2 + 1];
      }
    }
#pragma unroll
    for (int p = 0; p < 8; ++p) {
      int4 pk = {0, 0, 0, 0};
      if (q < N_) {
        int pd = p >> 2, dd = p & 3;
        float ox = OFFL[(size_t)q * 96 + h * 16 + pd * 8 + dd * 2 + 0];
        float oy = OFFL[(size_t)q * 96 + h * 16 + pd * 8 + dd * 2 + 1];
        float ix = rx[dd] * (float)WF_ + ox - 0.5f;
        float iy = ry[dd] * (float)HF_ + oy - 0.5f;
        float xf = floorf(ix), yf = floorf(iy);
        int x0 = (int)xf, y0 = (int)yf;
        float wx1 = ix - xf, wy1 = iy - yf;
        float wx0 = 1.f - wx1, wy0 = 1.f - wy1;
        float a = aw[p] * (float)sm;
        bool vx0 = (x0 >= 0) && (x0 < WF_);
        bool vx1 = (x0 + 1 >= 0) && (x0 + 1 < WF_);
        bool vy0 = (y0 >= 0) && (y0 < HF_);
        bool vy1 = (y0 + 1 >= 0) && (y0 + 1 < HF_);
        float w00 = (vx0 && vy0) ? wx0 * wy0 * a : 0.f;
        float w10 = (vx1 && vy0) ? wx1 * wy0 * a : 0.f;
        float w01 = (vx0 && vy1) ? wx0 * wy1 * a : 0.f;
        float w11 = (vx1 && vy1) ? wx1 * wy1 * a : 0.f;
        int yt = min(max(y0, 0), HF_ - 1) * WF_;
        int yb = min(max(y0 + 1, 0), HF_ - 1) * WF_;
        int xc0 = min(max(x0, 0), WF_ - 1);
        int xc1 = min(max(x0 + 1, 0), WF_ - 1);
        pk.x = yt | (yb << 16);
        pk.y = xc0 | (xc1 << 16);
        union { half2h hv; int iv; } u01, u23;
        u01.hv = (half2h){(_Float16)w00, (_Float16)w10};
        u23.hv = (half2h){(_Float16)w01, (_Float16)w11};
        pk.z = u01.iv;
        pk.w = u23.iv;
      }
      Pp[tid * 9 + p] = pk;
    }
  }
  __syncthreads();

  // ---- LDS gather: lane = (q:3 | rowsel | xsel | chalf) ------------------
  {
    int w = tid >> 6, lane = tid & 63;
    int qg = lane >> 3, c8 = lane & 7;
    int rowsel = (c8 >> 2) & 1, xsel = (c8 >> 1) & 1, chalf = c8 & 1;
    int role = c8 >> 1;
    int rsh = rowsel << 4, xsh = xsel << 4, wsh = (role & 1) << 4;

    for (int pass = 0; pass < CQ / 32; ++pass) {
      int ql = pass * 32 + w * 8 + qg;
      int q = q0 + ql;
      const int4* pp = &Pp[ql * 9];
      floatx2 acc[8] = {{0.f, 0.f}, {0.f, 0.f}, {0.f, 0.f}, {0.f, 0.f},
                        {0.f, 0.f}, {0.f, 0.f}, {0.f, 0.f}, {0.f, 0.f}};
#pragma unroll
      for (int p = 0; p < 8; ++p) {
        int4 prm = pp[p];
        int yoff = (prm.x >> rsh) & 0xffff;
        int xoff = (prm.y >> xsh) & 0xffff;
        int vidx = (yoff + xoff) * 2 + chalf;   // int4 index into Vl4
        unsigned wz = (unsigned)((role & 2) ? prm.w : prm.z);
        union { unsigned short u; _Float16 hf; } cu;
        cu.u = (unsigned short)((wz >> wsh) & 0xffffu);
        float wgt = (float)cu.hf;
        floatx2 wv = {wgt, wgt};
        int4 tv = Vl4[vidx];
        acc[0] += __builtin_amdgcn_cvt_pk_f32_fp8(tv.x, false) * wv;
        acc[1] += __builtin_amdgcn_cvt_pk_f32_fp8(tv.x, true)  * wv;
        acc[2] += __builtin_amdgcn_cvt_pk_f32_fp8(tv.y, false) * wv;
        acc[3] += __builtin_amdgcn_cvt_pk_f32_fp8(tv.y, true)  * wv;
        acc[4] += __builtin_amdgcn_cvt_pk_f32_fp8(tv.z, false) * wv;
        acc[5] += __builtin_amdgcn_cvt_pk_f32_fp8(tv.z, true)  * wv;
        acc[6] += __builtin_amdgcn_cvt_pk_f32_fp8(tv.w, false) * wv;
        acc[7] += __builtin_amdgcn_cvt_pk_f32_fp8(tv.w, true)  * wv;
      }
      float av[16];
#pragma unroll
      for (int k = 0; k < 8; ++k) {
        av[2 * k] = acc[k][0];
        av[2 * k + 1] = acc[k][1];
      }
#pragma unroll
      for (int k = 0; k < 16; ++k) av[k] += __shfl_xor(av[k], 2);  // xsel
#pragma unroll
      for (int k = 0; k < 16; ++k) av[k] += __shfl_xor(av[k], 4);  // rowsel
      if (c8 < 2 && q < N_) {
        float* dst = part + ((size_t)sh * N_ + q) * 32 + chalf * 16;
        *(float4*)(dst + 0)  = make_float4(av[0], av[1], av[2], av[3]);
        *(float4*)(dst + 4)  = make_float4(av[4], av[5], av[6], av[7]);
        *(float4*)(dst + 8)  = make_float4(av[8], av[9], av[10], av[11]);
        *(float4*)(dst + 12) = make_float4(av[12], av[13], av[14], av[15]);
      }
    }
  }
}

// ---------------------------------------------------------------------------
// reduce: slot[q] = (sum_s part[s*4+h][q]) / cnt(q); out = slot@w_out + b_out
// + query. 32-query tile per block, same micro-GEMM pattern as prep.
// ---------------------------------------------------------------------------
__global__ __launch_bounds__(256) void reduce_kernel(
    const float* __restrict__ part, const int* __restrict__ bev_mask,
    const float* __restrict__ query, const float* __restrict__ w_out,
    const float* __restrict__ b_out, float* __restrict__ out) {
  __shared__ float slds[32][132];
  __shared__ float sinv[32];
  int q0 = blockIdx.x * 32, tid = threadIdx.x;

  if (tid < 32) {
    int q = q0 + tid, cnt = 0;
    if (q < N_) {
#pragma unroll
      for (int s = 0; s < S_; ++s) {
        const int* bm = bev_mask + ((size_t)s * N_ + q) * D_;
        cnt += (bm[0] | bm[1] | bm[2] | bm[3]) ? 1 : 0;
      }
    }
    sinv[tid] = 1.f / (float)(cnt > 0 ? cnt : 1);
  }
  __syncthreads();

  {
    int ql = tid >> 3, c16 = (tid & 7) * 16;
    int q = q0 + ql, h = c16 >> 5, d0 = c16 & 31;
    float a[16];
#pragma unroll
    for (int k = 0; k < 16; ++k) a[k] = 0.f;
    if (q < N_) {
#pragma unroll
      for (int s = 0; s < S_; ++s) {
        const float* src = part + ((size_t)(s * H_ + h) * N_ + q) * 32 + d0;
#pragma unroll
        for (int k = 0; k < 16; k += 4) {
          float4 v = *(const float4*)(src + k);
          a[k + 0] += v.x; a[k + 1] += v.y; a[k + 2] += v.z; a[k + 3] += v.w;
        }
      }
    }
    float inv = sinv[ql];
    float* dst = &slds[ql][c16];
#pragma unroll
    for (int k = 0; k < 16; k += 4)
      *(float4*)(dst + k) =
          make_float4(a[k] * inv, a[k + 1] * inv, a[k + 2] * inv, a[k + 3] * inv);
  }
  __syncthreads();

  {
    int ci = tid & 31, mi = tid >> 5;
    int c0 = ci * 4, r0 = mi * 4;
    float acc[4][4];
#pragma unroll
    for (int j = 0; j < 4; ++j) {
      int q = q0 + r0 + j;
      int qq = (q < N_) ? q : (N_ - 1);
      float4 qv = *(const float4*)(query + (size_t)qq * C_ + c0);
      float4 bv = *(const float4*)(b_out + c0);
      acc[j][0] = bv.x + qv.x; acc[j][1] = bv.y + qv.y;
      acc[j][2] = bv.z + qv.z; acc[j][3] = bv.w + qv.w;
    }
#pragma unroll 2
    for (int k4 = 0; k4 < C_; k4 += 4) {
      float bf[16];
#pragma unroll
      for (int kk = 0; kk < 4; ++kk) {
        float4 b4 = *(const float4*)(w_out + (size_t)(k4 + kk) * C_ + c0);
        bf[kk * 4 + 0] = b4.x; bf[kk * 4 + 1] = b4.y;
        bf[kk * 4 + 2] = b4.z; bf[kk * 4 + 3] = b4.w;
      }
      float af[16];
#pragma unroll
      for (int j = 0; j < 4; ++j) {
        float4 a4 = *(const float4*)(&slds[r0 + j][k4]);
        af[j * 4 + 0] = a4.x; af[j * 4 + 1] = a4.y;
        af[j * 4 + 2] = a4.z; af[j * 4 + 3] = a4.w;
      }
#pragma unroll
      for (int j = 0; j < 4; ++j)
#pragma unroll
        for (int kk = 0; kk < 4; ++kk)
#pragma unroll
          for (int cc = 0; cc < 4; ++cc)
            acc[j][cc] = fmaf(af[j * 4 + kk], bf[kk * 4 + cc], acc[j][cc]);
    }
#pragma unroll
    for (int j = 0; j < 4; ++j) {
      int q = q0 + r0 + j;
      if (q < N_)
        *(float4*)(out + (size_t)q * C_ + c0) =
            make_float4(acc[j][0], acc[j][1], acc[j][2], acc[j][3]);
    }
  }
}

// ---------------------------------------------------------------------------
extern "C" void kernel_launch(void* const* d_in, const int* in_sizes, int n_in,
                              void* d_out, int out_size, void* d_ws, size_t ws_size,
                              hipStream_t stream) {
  const float* query     = (const float*)d_in[0];
  const float* value     = (const float*)d_in[2];
  const float* query_pos = (const float*)d_in[3];
  const float* refpts    = (const float*)d_in[4];
  const int*   bev_mask  = (const int*)d_in[5];
  const float* w_off     = (const float*)d_in[6];
  const float* b_off     = (const float*)d_in[7];
  const float* w_attn    = (const float*)d_in[8];
  const float* b_attn    = (const float*)d_in[9];
  const float* w_val     = (const float*)d_in[10];
  const float* b_val     = (const float*)d_in[11];
  const float* w_out     = (const float*)d_in[12];
  const float* b_out     = (const float*)d_in[13];

  char* ws = (char*)d_ws;
  char* vh8   = ws + 64;                                        // ABYTES
  float* OFFL = (float*)(ws + 64 + 2 * (size_t)ABYTES + 64);    // 3,840,000 B
  float* PART = (float*)(ws + 64 + 2 * (size_t)ABYTES + 64 +
                         (size_t)N_ * 96 * 4);                  // 30,720,000 B

  prep_kernel<<<NB_V + NB_O, 256, 0, stream>>>(
      value, w_val, b_val, vh8, query, query_pos, w_off, b_off, w_attn, b_attn,
      OFFL);
  attn3_kernel<<<NSH * NCH, 256, 0, stream>>>(OFFL, refpts, bev_mask, ws,
                                              PART);
  reduce_kernel<<<(N_ + 31) / 32, 256, 0, stream>>>(PART, bev_mask, query,
                                                    w_out, b_out,
                                                    (float*)d_out);
}